// Round 1
// 328.680 us; speedup vs baseline: 1.0055x; 1.0055x over previous
//
#include <hip/hip_runtime.h>
#include <stdint.h>

// Problem constants (from reference setup_inputs)
#define B_DIM   16384
#define IN_DIM  2048
#define OUT_DIM 2048
#define BN_EPS  1e-5f

typedef int    i32x4 __attribute__((ext_vector_type(4)));
typedef unsigned short u16x4 __attribute__((ext_vector_type(4)));

// ---------- helpers ----------

__device__ __forceinline__ unsigned short f2bf_rne(float f) {
    unsigned u = __builtin_bit_cast(unsigned, f);
    return (unsigned short)((u + 0x7fffu + ((u >> 16) & 1u)) >> 16);
}
__device__ __forceinline__ float bf2f(unsigned short h) {
    unsigned u = ((unsigned)h) << 16;
    return __builtin_bit_cast(float, u);
}

// async global->LDS, 16B per lane. LDS dst = wave-uniform base + lane*16.
__device__ __forceinline__ void gl_lds16(const void* g, void* l) {
    __builtin_amdgcn_global_load_lds(
        (const __attribute__((address_space(1))) unsigned int*)g,
        (__attribute__((address_space(3))) unsigned int*)l,
        16, 0, 0);
}

__device__ __forceinline__ int pack4(float a, float b, float c, float d, float inv) {
    int q0 = (int)rintf(a * inv) & 255;
    int q1 = (int)rintf(b * inv) & 255;
    int q2 = (int)rintf(c * inv) & 255;
    int q3 = (int)rintf(d * inv) & 255;
    return q0 | (q1 << 8) | (q2 << 16) | (q3 << 24);
}

// ---------- kernel 1: x fp32 -> i8 with per-row scale ----------
__global__ __launch_bounds__(256) void quantize_x_kernel(
        const float4* __restrict__ x4, int* __restrict__ xq,
        float* __restrict__ scales) {
    __shared__ float wmax[4];
    const int row = blockIdx.x;
    const int t = threadIdx.x;
    const float4* xr = x4 + (size_t)row * 512;
    float4 a = xr[t];          // 16B coalesced
    float4 b = xr[t + 256];
    float m = fmaxf(fmaxf(fabsf(a.x), fabsf(a.y)), fmaxf(fabsf(a.z), fabsf(a.w)));
    m = fmaxf(m, fmaxf(fmaxf(fabsf(b.x), fabsf(b.y)), fmaxf(fabsf(b.z), fabsf(b.w))));
#pragma unroll
    for (int off = 32; off >= 1; off >>= 1) m = fmaxf(m, __shfl_xor(m, off));
    if ((t & 63) == 0) wmax[t >> 6] = m;
    __syncthreads();
    m = fmaxf(fmaxf(wmax[0], wmax[1]), fmaxf(wmax[2], wmax[3]));
    m = fmaxf(m, 1e-20f);                 // guard all-zero row
    const float inv = 127.0f / m;
    if (t == 0) scales[row] = m * (1.0f / 127.0f);
    int* xo = xq + (size_t)row * 512;
    xo[t]       = pack4(a.x, a.y, a.z, a.w, inv);   // 4B coalesced
    xo[t + 256] = pack4(b.x, b.y, b.z, b.w, inv);
}

// ---------- kernel 2: w fp32 -> sign i8 (+1/-1); also zero stat accums ----------
__global__ __launch_bounds__(256) void convert_w_kernel(
        const float4* __restrict__ w, int* __restrict__ wq,
        float4* __restrict__ stats /* colsum[2048]+colsumsq[2048] */) {
    int id = blockIdx.x * 256 + threadIdx.x;       // exact: 4096 blocks
    if (id < 1024) stats[id] = make_float4(0.f, 0.f, 0.f, 0.f);
    float4 a = w[id];
    int b0 = (a.x < 0.f) ? 0xFF : 0x01;
    int b1 = (a.y < 0.f) ? 0xFF : 0x01;
    int b2 = (a.z < 0.f) ? 0xFF : 0x01;
    int b3 = (a.w < 0.f) ? 0xFF : 0x01;
    wq[id] = b0 | (b1 << 8) | (b2 << 16) | (b3 << 24);
}

// ---------- kernel 3: i8 GEMM (NT) 256x256 tile, 8-wave, phase-pipelined ----------
// A: [B_DIM, IN_DIM] i8; Bw: [OUT_DIM, IN_DIM] i8 (+1/-1). D = i32 exact dot;
// Y[m][n] = scales[m] * D[m][n], stored bf16; column sum/sumsq accumulated fp32.
//
// Structure (T2+T3+T4+T5 per the 256^2 8-phase template, ported to i8):
//  - tile 256x256, BK=128 bytes; 16 K-tiles; 512 threads = 8 waves (2M x 4N)
//  - LDS 128 KiB: double-buffered A[256][128] + B[256][128]
//  - LDS XOR-swizzle: 16B-slot ^= (row&7). global_load_lds writes linearly, so
//    the swizzle is applied by permuting the per-lane GLOBAL source k-chunk
//    (inverse==same involution) and XOR-ing the ds_read slot (rule #21).
//    Read banks: 8 slots x 4 banks, 2-way aliasing -> conflict-free.
//  - 4 phases per K-tile: {ds_read subtile | stage sweeps | [vmcnt] | barrier |
//    lgkmcnt(0) | setprio(1) 16xMFMA setprio(0) | barrier}
//  - counted vmcnt: sweeps issued in order B0,B1,B2,B3 (phase0) A0,A2,A1,A3
//    (phase1). phase0 waits vmcnt(4) (drains prev tile's A1,A3 before phase1
//    reads them), phase3 waits vmcnt(2) (drains B0-3,A0,A2 of next tile; the
//    2 left in flight are A1,A3 which phase0/2 never read). Never vmcnt(0) in
//    steady state.
__global__ __launch_bounds__(512, 2) void gemm_bn_kernel(
        const char* __restrict__ A, const char* __restrict__ Bw,
        const float* __restrict__ scales,
        unsigned short* __restrict__ Yb,
        float* __restrict__ colsum, float* __restrict__ colsumsq) {
    __shared__ __align__(16) char smem[131072];  // [2 buf][A 32K | B 32K]

    const int tid  = threadIdx.x;
    const int wave = tid >> 6;
    const int lane = tid & 63;
    const int wm = wave >> 2;         // wave row (0..1) -> 128 rows of M
    const int wn = wave & 3;          // wave col (0..3) -> 64 cols of N
    const int lr = lane & 15;
    const int lq = lane >> 4;

    // XCD swizzle (512 blocks, 512%8==0 -> simple bijection)
    const int b  = blockIdx.x;                 // 0..511
    const int lb = (b & 7) * 64 + (b >> 3);
    const int bm = (lb >> 3) * 256;            // 64 M tiles
    const int bn = (lb & 7) * 256;             // 8 N tiles

    // ---- staging addressing ----
    // sweep = 64 rows x 128B = 8KB = 512 threads x 16B. thread's row-in-sweep
    // = tid>>3, slot = tid&7. LDS dest linear; global source k-chunk is
    // slot ^ (row&7)  (row&7 == (tid>>3)&7 since sweep base rows are %8==0).
    const int swz16 = (((tid & 7) ^ ((tid >> 3) & 7)) << 4);
    const char* gA = A  + (size_t)(bm + (tid >> 3)) * IN_DIM + swz16;
    const char* gB = Bw + (size_t)(bn + (tid >> 3)) * IN_DIM + swz16;
    const int ldst = tid << 4;

    // ---- ds-read addressing ----
    // frag(i,kk): row = wm*128 + i*16 + lr (x128B), slot = (kk*4+lq)^(lr&7)
    const int aRd = wm * 16384 + lr * 128;
    const int bRd = wn * 8192  + lr * 128;
    const int sl0 = ((lq    ) ^ (lr & 7)) << 4;
    const int sl1 = ((lq + 4) ^ (lr & 7)) << 4;

    i32x4 acc[8][4];
#pragma unroll
    for (int i = 0; i < 8; ++i)
#pragma unroll
        for (int j = 0; j < 4; ++j) {
            i32x4 z = {0, 0, 0, 0};
            acc[i][j] = z;
        }

#define VM_WAIT(N) asm volatile("s_waitcnt vmcnt(" #N ")" ::: "memory")
#define LGKM0()    asm volatile("s_waitcnt lgkmcnt(0)" ::: "memory")
#define BAR()      __builtin_amdgcn_s_barrier()

#define MM16(IB) \
    _Pragma("unroll") for (int i = 0; i < 4; ++i) \
    _Pragma("unroll") for (int j = 0; j < 4; ++j) \
        acc[(IB) + i][j] = __builtin_amdgcn_mfma_i32_16x16x64_i8( \
            av[i], bv[j], acc[(IB) + i][j], 0, 0, 0)

    // prologue: stage tile 0 into buffer 0 (order B0-3, A0, A2, A1, A3)
    {
        char* An = smem;
        char* Bn = smem + 32768;
        gl_lds16(gB + 0 * 131072, Bn + 0 * 8192 + ldst);
        gl_lds16(gB + 1 * 131072, Bn + 1 * 8192 + ldst);
        gl_lds16(gB + 2 * 131072, Bn + 2 * 8192 + ldst);
        gl_lds16(gB + 3 * 131072, Bn + 3 * 8192 + ldst);
        gl_lds16(gA + 0 * 131072, An + 0 * 8192 + ldst);
        gl_lds16(gA + 2 * 131072, An + 2 * 8192 + ldst);
        gl_lds16(gA + 1 * 131072, An + 1 * 8192 + ldst);
        gl_lds16(gA + 3 * 131072, An + 3 * 8192 + ldst);
        VM_WAIT(2);                // B0-3,A0,A2 landed; A1,A3 stay in flight
        BAR();
    }

#define GTILE(t_, LAST_) do {                                                  \
    const char* Ab = smem + (((t_) & 1) ? 65536 : 0);                          \
    const char* Bb = Ab + 32768;                                               \
    char* An = smem + (((t_) & 1) ? 0 : 65536);                                \
    char* Bn = An + 32768;                                                     \
    const size_t kn = (size_t)((t_) + 1) * 128;                                \
    i32x4 av[4], bv[4];                                                        \
    /* phase 0: kk=0, i=0..3 (needs B0-3, A0, A2 of cur) */                    \
    _Pragma("unroll") for (int j = 0; j < 4; ++j)                              \
        bv[j] = *(const i32x4*)(Bb + bRd + j * 2048 + sl0);                    \
    _Pragma("unroll") for (int i = 0; i < 4; ++i)                              \
        av[i] = *(const i32x4*)(Ab + aRd + i * 2048 + sl0);                    \
    if (!(LAST_)) {                                                            \
        gl_lds16(gB + kn          , Bn + 0 * 8192 + ldst);                     \
        gl_lds16(gB + kn + 131072 , Bn + 1 * 8192 + ldst);                     \
        gl_lds16(gB + kn + 262144 , Bn + 2 * 8192 + ldst);                     \
        gl_lds16(gB + kn + 393216 , Bn + 3 * 8192 + ldst);                     \
    }                                                                          \
    if (LAST_) { VM_WAIT(0); } else { VM_WAIT(4); } /* drain cur A1,A3 */      \
    BAR(); LGKM0();                                                            \
    __builtin_amdgcn_s_setprio(1);                                             \
    MM16(0);                                                                   \
    __builtin_amdgcn_s_setprio(0);                                             \
    BAR();                                                                     \
    /* phase 1: kk=0, i=4..7 (needs A1, A3 of cur; bv reused) */               \
    _Pragma("unroll") for (int i = 0; i < 4; ++i)                              \
        av[i] = *(const i32x4*)(Ab + aRd + (i + 4) * 2048 + sl0);              \
    if (!(LAST_)) {                                                            \
        gl_lds16(gA + kn          , An + 0 * 8192 + ldst);                     \
        gl_lds16(gA + kn + 262144 , An + 2 * 8192 + ldst);                     \
        gl_lds16(gA + kn + 131072 , An + 1 * 8192 + ldst);                     \
        gl_lds16(gA + kn + 393216 , An + 3 * 8192 + ldst);                     \
    }                                                                          \
    BAR(); LGKM0();                                                            \
    __builtin_amdgcn_s_setprio(1);                                             \
    MM16(4);                                                                   \
    __builtin_amdgcn_s_setprio(0);                                             \
    BAR();                                                                     \
    /* phase 2: kk=1, i=0..3 (cur fully resident) */                           \
    _Pragma("unroll") for (int j = 0; j < 4; ++j)                              \
        bv[j] = *(const i32x4*)(Bb + bRd + j * 2048 + sl1);                    \
    _Pragma("unroll") for (int i = 0; i < 4; ++i)                              \
        av[i] = *(const i32x4*)(Ab + aRd + i * 2048 + sl1);                    \
    BAR(); LGKM0();                                                            \
    __builtin_amdgcn_s_setprio(1);                                             \
    MM16(0);                                                                   \
    __builtin_amdgcn_s_setprio(0);                                             \
    BAR();                                                                     \
    /* phase 3: kk=1, i=4..7; drain nxt B0-3,A0,A2 (leave A1,A3 in flight) */  \
    _Pragma("unroll") for (int i = 0; i < 4; ++i)                              \
        av[i] = *(const i32x4*)(Ab + aRd + (i + 4) * 2048 + sl1);              \
    VM_WAIT(2);                                                                \
    BAR(); LGKM0();                                                            \
    __builtin_amdgcn_s_setprio(1);                                             \
    MM16(4);                                                                   \
    __builtin_amdgcn_s_setprio(0);                                             \
    BAR();                                                                     \
} while (0)

    for (int t = 0; t < 15; ++t) GTILE(t, 0);
    GTILE(15, 1);

#undef GTILE
#undef MM16
#undef VM_WAIT
#undef LGKM0
#undef BAR

    // epilogue: y = scales[m] * acc (C/D layout: col = lr, row = lq*4 + r)
    float colS[4], colQ[4];
#pragma unroll
    for (int j = 0; j < 4; ++j) { colS[j] = 0.f; colQ[j] = 0.f; }

#pragma unroll
    for (int i = 0; i < 8; ++i) {
        const int row0 = bm + wm * 128 + i * 16 + lq * 4;
        float sc[4];
#pragma unroll
        for (int r = 0; r < 4; ++r) sc[r] = scales[row0 + r];
#pragma unroll
        for (int r = 0; r < 4; ++r) {
            size_t base = (size_t)(row0 + r) * OUT_DIM + bn + wn * 64 + lr;
#pragma unroll
            for (int j = 0; j < 4; ++j) {
                float v = (float)acc[i][j][r] * sc[r];
                Yb[base + j * 16] = f2bf_rne(v);
                colS[j] += v;
                colQ[j] += v * v;
            }
        }
    }

    // per-column partial sum / sumsq -> atomics (combine 4 quads = 4 row groups)
#pragma unroll
    for (int j = 0; j < 4; ++j) {
        float s = colS[j], q = colQ[j];
        s += __shfl_xor(s, 16); s += __shfl_xor(s, 32);
        q += __shfl_xor(q, 16); q += __shfl_xor(q, 32);
        if (lq == 0) {
            int col = bn + wn * 64 + j * 16 + lr;
            atomicAdd(&colsum[col], s);
            atomicAdd(&colsumsq[col], q);
        }
    }
}

// ---------- kernel 4: finalize BN params ----------
__global__ __launch_bounds__(256) void finalize_kernel(
        const float* __restrict__ colsum, const float* __restrict__ colsumsq,
        const float* __restrict__ gamma, const float* __restrict__ beta,
        float* __restrict__ scale, float* __restrict__ bias) {
    int n = blockIdx.x * 256 + threadIdx.x;
    if (n < OUT_DIM) {
        const float inv = 1.f / (float)B_DIM;
        float mean = colsum[n] * inv;
        float var  = colsumsq[n] * inv - mean * mean;
        float sc   = gamma[n] * rsqrtf(var + BN_EPS);
        scale[n] = sc;
        bias[n]  = beta[n] - mean * sc;
    }
}

// ---------- kernel 5: bf16 Y -> affine+ReLU -> fp32 out. 8 elems/thread ----------
__global__ __launch_bounds__(256) void bn_relu_bf16_kernel(
        const u16x4* __restrict__ yb, float4* __restrict__ out,
        const float4* __restrict__ scale4, const float4* __restrict__ bias4) {
    int base = blockIdx.x * 512 + threadIdx.x;   // block covers 512 f4-groups
#pragma unroll
    for (int p = 0; p < 2; ++p) {
        int id = base + p * 256;                 // coalesced both passes
        int c4 = id & (OUT_DIM / 4 - 1);         // column group (2048%4==0)
        u16x4 h = yb[id];                        // 8B coalesced read
        float4 s = scale4[c4];
        float4 bb = bias4[c4];
        float4 v;
        v.x = fmaxf(fmaf(bf2f(h[0]), s.x, bb.x), 0.f);
        v.y = fmaxf(fmaf(bf2f(h[1]), s.y, bb.y), 0.f);
        v.z = fmaxf(fmaf(bf2f(h[2]), s.z, bb.z), 0.f);
        v.w = fmaxf(fmaf(bf2f(h[3]), s.w, bb.w), 0.f);
        out[id] = v;                             // 16B coalesced write
    }
}

// ---------- launch ----------
extern "C" void kernel_launch(void* const* d_in, const int* in_sizes, int n_in,
                              void* d_out, int out_size, void* d_ws, size_t ws_size,
                              hipStream_t stream) {
    const float* x     = (const float*)d_in[0];   // [16384, 2048]
    const float* w     = (const float*)d_in[1];   // [2048, 2048]
    const float* gamma = (const float*)d_in[2];   // [2048]
    const float* beta  = (const float*)d_in[3];   // [2048]
    float* out = (float*)d_out;                   // [16384, 2048]

    char* ws = (char*)d_ws;
    // ws layout: xq 32MB | wq 4MB | yb 64MB | stats 32KB | scales 64KB
    const size_t XQ_OFF = 0;
    const size_t WQ_OFF = XQ_OFF + (size_t)B_DIM * IN_DIM;          // 33,554,432
    const size_t YB_OFF = WQ_OFF + (size_t)OUT_DIM * IN_DIM;        // 37,748,736
    const size_t ST_OFF = YB_OFF + (size_t)B_DIM * OUT_DIM * 2;     // 104,857,600
    const size_t SC_OFF = ST_OFF + 8192 * 4;                        // 104,890,368

    char* xq = ws + XQ_OFF;
    char* wq = ws + WQ_OFF;
    unsigned short* yb = (unsigned short*)(ws + YB_OFF);
    float* colsum   = (float*)(ws + ST_OFF);
    float* colsumsq = colsum + 2048;
    float* scale    = colsum + 4096;
    float* bias     = colsum + 6144;
    float* scales   = (float*)(ws + SC_OFF);      // per-row x scales [16384]

    quantize_x_kernel<<<B_DIM, 256, 0, stream>>>(
        (const float4*)x, (int*)xq, scales);
    convert_w_kernel<<<4096, 256, 0, stream>>>(
        (const float4*)w, (int*)wq, (float4*)colsum);
    gemm_bn_kernel<<<512, 512, 0, stream>>>(
        xq, wq, scales, yb, colsum, colsumsq);
    finalize_kernel<<<8, 256, 0, stream>>>(
        colsum, colsumsq, gamma, beta, scale, bias);
    bn_relu_bf16_kernel<<<16384, 256, 0, stream>>>(
        (const u16x4*)yb, (float4*)out, (const float4*)scale,
        (const float4*)bias);
}